// Round 1
// baseline (482.803 us; speedup 1.0000x reference)
//
#include <hip/hip_runtime.h>
#include <math.h>

#define BATCH   4
#define SEQLEN  2048
#define HIDDEN  1024
#define NMODES  32   // N2 = STATE/2 complex modes

// One 32-lane group per (b,h) channel, one lane per complex mode.
// Block = 256 threads = 8 channels. Grid = 4096/8 = 512 blocks.
__global__ void ssm_scan_kernel(
    const float* __restrict__ input,   // [B, L, H]
    const float* __restrict__ log_dt,  // [H]
    const float* __restrict__ Dp,      // [H]
    const float* __restrict__ A_log,   // [H, N2]
    const float* __restrict__ A_imag,  // [H, N2]
    const float* __restrict__ Bp,      // [H, N2, 2]
    const float* __restrict__ Cp,      // [H, N2, 2]
    float* __restrict__ out)           // [B, L, H]
{
    const int tid = threadIdx.x;
    const int grp = tid >> 5;                 // channel-in-block 0..7
    const int n   = tid & 31;                 // mode 0..31
    const int c   = blockIdx.x * 8 + grp;     // global channel 0..4095
    const int h   = c & (HIDDEN - 1);
    const int b   = c >> 10;                  // c / HIDDEN

    // ---- per-(h,n) coefficient computation (bilinear / GBT alpha=0.5) ----
    const int idx = h * NMODES + n;
    const float dt     = expf(log_dt[h]);
    const float halfdt = 0.5f * dt;
    const float ar = -expf(A_log[idx]);       // Re(A)
    const float ai = A_imag[idx];             // Im(A)

    // denom = 1 - dt/2 * A
    const float dr = 1.0f - halfdt * ar;
    const float di = -halfdt * ai;
    const float inv = 1.0f / (dr * dr + di * di);

    // A_disc = (1 + dt/2 A) / denom
    const float nr = 1.0f + halfdt * ar;
    const float ni = halfdt * ai;
    const float adr = (nr * dr + ni * di) * inv;
    const float adi = (ni * dr - nr * di) * inv;

    // B_disc = dt * B / denom
    const float tbr = dt * Bp[idx * 2 + 0];
    const float tbi = dt * Bp[idx * 2 + 1];
    const float bdr = (tbr * dr + tbi * di) * inv;
    const float bdi = (tbi * dr - tbr * di) * inv;

    // Cc = 2*(C0 + i C1);  y partial = Re(Cc * x) = cr*xr - ci*xi
    const float cr     = 2.0f * Cp[idx * 2 + 0];
    const float ci_neg = -2.0f * Cp[idx * 2 + 1];

    const float Dh = Dp[h];

    const float* ip = input + (size_t)b * SEQLEN * HIDDEN + h;
    float*       op = out   + (size_t)b * SEQLEN * HIDDEN + h;

    float xr = 0.0f, xi = 0.0f;

    #pragma unroll 1
    for (int t0 = 0; t0 < SEQLEN; t0 += 8) {
        // prefetch 8 inputs (independent of the recurrence chain)
        float u[8];
        #pragma unroll
        for (int j = 0; j < 8; ++j)
            u[j] = ip[(size_t)(t0 + j) * HIDDEN];

        #pragma unroll
        for (int j = 0; j < 8; ++j) {
            const float uu = u[j];
            // x = A_disc * x + B_disc * u   (complex, diagonal)
            const float nxr = fmaf(adr, xr, fmaf(-adi, xi, bdr * uu));
            const float nxi = fmaf(adi, xr, fmaf( adr, xi, bdi * uu));
            xr = nxr; xi = nxi;

            // partial of Re(Cc . x)
            float p = fmaf(cr, xr, ci_neg * xi);

            // reduce across the 32 modes (masks <=16 stay in 32-lane halves)
            p += __shfl_xor(p, 1);
            p += __shfl_xor(p, 2);
            p += __shfl_xor(p, 4);
            p += __shfl_xor(p, 8);
            p += __shfl_xor(p, 16);

            if (n == 0)
                op[(size_t)(t0 + j) * HIDDEN] = fmaf(Dh, uu, p);
        }
    }
}

extern "C" void kernel_launch(void* const* d_in, const int* in_sizes, int n_in,
                              void* d_out, int out_size, void* d_ws, size_t ws_size,
                              hipStream_t stream) {
    const float* input  = (const float*)d_in[0];
    const float* log_dt = (const float*)d_in[1];
    const float* Dp     = (const float*)d_in[2];
    const float* A_log  = (const float*)d_in[3];
    const float* A_imag = (const float*)d_in[4];
    const float* Bp     = (const float*)d_in[5];
    const float* Cp     = (const float*)d_in[6];
    float* out = (float*)d_out;

    const int channels = BATCH * HIDDEN;          // 4096
    dim3 grid(channels / 8), block(256);
    ssm_scan_kernel<<<grid, block, 0, stream>>>(
        input, log_dt, Dp, A_log, A_imag, Bp, Cp, out);
}

// Round 2
// 297.127 us; speedup vs baseline: 1.6249x; 1.6249x over previous
//
#include <hip/hip_runtime.h>
#include <math.h>

#define BATCH   4
#define SEQLEN  2048
#define HIDDEN  1024
#define NMODES  32   // N2 = STATE/2 complex modes

// DPP-based cross-lane add: VALU-only, no LDS pipe.
// ctrl: 0xB1 = quad_perm xor1, 0x4E = quad_perm xor2,
//       0x124 = row_ror:4, 0x128 = row_ror:8, 0x142 = row_bcast15
template <int CTRL>
__device__ __forceinline__ float dpp_add(float p) {
    int t = __builtin_amdgcn_update_dpp(0, __float_as_int(p), CTRL, 0xF, 0xF, true);
    return p + __int_as_float(t);
}

// One 32-lane group per (b,h) channel, one lane per complex mode.
// Block = 256 threads = 8 channels. Grid = 4096/8 = 512 blocks.
__global__ void ssm_scan_kernel(
    const float* __restrict__ input,   // [B, L, H]
    const float* __restrict__ log_dt,  // [H]
    const float* __restrict__ Dp,      // [H]
    const float* __restrict__ A_log,   // [H, N2]
    const float* __restrict__ A_imag,  // [H, N2]
    const float* __restrict__ Bp,      // [H, N2, 2]
    const float* __restrict__ Cp,      // [H, N2, 2]
    float* __restrict__ out)           // [B, L, H]
{
    const int tid = threadIdx.x;
    const int grp = tid >> 5;                 // channel-in-block 0..7
    const int n   = tid & 31;                 // mode 0..31
    const int c   = blockIdx.x * 8 + grp;     // global channel 0..4095
    const int h   = c & (HIDDEN - 1);
    const int b   = c >> 10;                  // c / HIDDEN

    // ---- per-(h,n) coefficient computation (bilinear / GBT alpha=0.5) ----
    const int idx = h * NMODES + n;
    const float dt     = expf(log_dt[h]);
    const float halfdt = 0.5f * dt;
    const float ar = -expf(A_log[idx]);       // Re(A)
    const float ai = A_imag[idx];             // Im(A)

    // denom = 1 - dt/2 * A
    const float dr = 1.0f - halfdt * ar;
    const float di = -halfdt * ai;
    const float inv = 1.0f / (dr * dr + di * di);

    // A_disc = (1 + dt/2 A) / denom
    const float nr = 1.0f + halfdt * ar;
    const float ni = halfdt * ai;
    const float adr = (nr * dr + ni * di) * inv;
    const float adi = (ni * dr - nr * di) * inv;
    const float nadi = -adi;

    // B_disc = dt * B / denom
    const float tbr = dt * Bp[idx * 2 + 0];
    const float tbi = dt * Bp[idx * 2 + 1];
    const float bdr = (tbr * dr + tbi * di) * inv;
    const float bdi = (tbi * dr - tbr * di) * inv;

    // Cc = 2*(C0 + i C1);  y partial = Re(Cc * x) = cr*xr - ci*xi
    const float cr     = 2.0f * Cp[idx * 2 + 0];
    const float ci_neg = -2.0f * Cp[idx * 2 + 1];

    const float Dh = Dp[h];

    const float* ip = input + (size_t)b * SEQLEN * HIDDEN + h;
    float*       op = out   + (size_t)b * SEQLEN * HIDDEN + h;

    float xr = 0.0f, xi = 0.0f;

    #pragma unroll 1
    for (int t0 = 0; t0 < SEQLEN; t0 += 8) {
        // prefetch 8 inputs (independent of the recurrence chain)
        float u[8];
        #pragma unroll
        for (int j = 0; j < 8; ++j)
            u[j] = ip[(size_t)(t0 + j) * HIDDEN];

        #pragma unroll
        for (int j = 0; j < 8; ++j) {
            const float uu = u[j];
            // x = A_disc * x + B_disc * u   (complex, diagonal)
            const float nxr = fmaf(adr, xr, fmaf(nadi, xi, bdr * uu));
            const float nxi = fmaf(adi, xr, fmaf(adr,  xi, bdi * uu));
            xr = nxr; xi = nxi;

            // partial of Re(Cc . x)
            float p = fmaf(cr, xr, ci_neg * xi);

            // 32-lane sum via DPP (VALU-only). After the 4 in-row stages all
            // 16 lanes of a row hold the row sum; row_bcast15 adds row0's sum
            // into row1 (and row2 -> row3): total lands in lanes 16 / 48.
            p = dpp_add<0xB1>(p);    // + xor1  (quad_perm 1,0,3,2)
            p = dpp_add<0x4E>(p);    // + xor2  (quad_perm 2,3,0,1)
            p = dpp_add<0x124>(p);   // + row_ror:4
            p = dpp_add<0x128>(p);   // + row_ror:8
            p = dpp_add<0x142>(p);   // + row_bcast15 (cross-row; lands in upper row)

            if (n == 16)
                op[(size_t)(t0 + j) * HIDDEN] = fmaf(Dh, uu, p);
        }
    }
}

extern "C" void kernel_launch(void* const* d_in, const int* in_sizes, int n_in,
                              void* d_out, int out_size, void* d_ws, size_t ws_size,
                              hipStream_t stream) {
    const float* input  = (const float*)d_in[0];
    const float* log_dt = (const float*)d_in[1];
    const float* Dp     = (const float*)d_in[2];
    const float* A_log  = (const float*)d_in[3];
    const float* A_imag = (const float*)d_in[4];
    const float* Bp     = (const float*)d_in[5];
    const float* Cp     = (const float*)d_in[6];
    float* out = (float*)d_out;

    const int channels = BATCH * HIDDEN;          // 4096
    dim3 grid(channels / 8), block(256);
    ssm_scan_kernel<<<grid, block, 0, stream>>>(
        input, log_dt, Dp, A_log, A_imag, Bp, Cp, out);
}

// Round 3
// 167.141 us; speedup vs baseline: 2.8886x; 1.7777x over previous
//
#include <hip/hip_runtime.h>
#include <math.h>

#define BATCH    4
#define SEQLEN   2048
#define HIDDEN   1024
#define NMODES   32                  // N2 = STATE/2 complex modes
#define NCHUNK   8
#define CHUNKLEN (SEQLEN / NCHUNK)   // 256
#define CHANNELS (BATCH * HIDDEN)    // 4096

// DPP-based cross-lane add: VALU-only, no LDS pipe.
// ctrl: 0xB1 quad_perm xor1, 0x4E quad_perm xor2, 0x124 row_ror:4,
//       0x128 row_ror:8, 0x142 row_bcast15
template <int CTRL>
__device__ __forceinline__ float dpp_add(float p) {
    int t = __builtin_amdgcn_update_dpp(0, __float_as_int(p), CTRL, 0xF, 0xF, true);
    return p + __int_as_float(t);
}

// Shared coefficient math (bilinear / GBT alpha=0.5), per (h, n):
// A_disc = (1 + dt/2 A)/(1 - dt/2 A), B_disc = dt B / (1 - dt/2 A)
__device__ __forceinline__ void make_coefs(
    const float* log_dt, const float* A_log, const float* A_imag,
    const float* Bp, int h, int n,
    float& adr, float& adi, float& bdr, float& bdi)
{
    const int idx = h * NMODES + n;
    const float dt     = expf(log_dt[h]);
    const float halfdt = 0.5f * dt;
    const float ar = -expf(A_log[idx]);
    const float ai = A_imag[idx];
    const float dr = 1.0f - halfdt * ar;
    const float di = -halfdt * ai;
    const float inv = 1.0f / (dr * dr + di * di);
    const float nr = 1.0f + halfdt * ar;
    const float ni = halfdt * ai;
    adr = (nr * dr + ni * di) * inv;
    adi = (ni * dr - nr * di) * inv;
    const float tbr = dt * Bp[idx * 2 + 0];
    const float tbi = dt * Bp[idx * 2 + 1];
    bdr = (tbr * dr + tbi * di) * inv;
    bdi = (tbi * dr - tbr * di) * inv;
}

// Kernel 1: per (channel, chunk 0..NCHUNK-2) scan states only from x=0.
// Writes chunk-end state to states[chunk][channel][mode].
__global__ void ssm_chunk_states(
    const float* __restrict__ input,
    const float* __restrict__ log_dt,
    const float* __restrict__ A_log,
    const float* __restrict__ A_imag,
    const float* __restrict__ Bp,
    float2* __restrict__ states)
{
    const int tid   = threadIdx.x;
    const int grp   = tid >> 5;
    const int n     = tid & 31;
    const int g     = blockIdx.x * 8 + grp;        // chunk-major group id
    const int ch    = g & (CHANNELS - 1);
    const int chunk = g >> 12;                     // 0..NCHUNK-2
    const int h     = ch & (HIDDEN - 1);
    const int b     = ch >> 10;

    float adr, adi, bdr, bdi;
    make_coefs(log_dt, A_log, A_imag, Bp, h, n, adr, adi, bdr, bdi);
    const float nadi = -adi;

    const float* ip = input + ((size_t)b * SEQLEN + (size_t)chunk * CHUNKLEN) * HIDDEN + h;

    float xr = 0.0f, xi = 0.0f;
    #pragma unroll 1
    for (int t0 = 0; t0 < CHUNKLEN; t0 += 8) {
        float u[8];
        #pragma unroll
        for (int j = 0; j < 8; ++j)
            u[j] = ip[(size_t)(t0 + j) * HIDDEN];
        #pragma unroll
        for (int j = 0; j < 8; ++j) {
            const float uu = u[j];
            const float nxr = fmaf(adr, xr, fmaf(nadi, xi, bdr * uu));
            const float nxi = fmaf(adi, xr, fmaf(adr,  xi, bdi * uu));
            xr = nxr; xi = nxi;
        }
    }
    states[((size_t)chunk * CHANNELS + ch) * NMODES + n] = make_float2(xr, xi);
}

// Kernel 2: per (channel, chunk 0..NCHUNK-1): reconstruct true chunk-start
// state via Horner over previous chunk-end states with Apow = A_disc^CHUNKLEN,
// fold Cc into the state (v = Cc .* x), scan the chunk, write y.
__global__ void ssm_chunk_scan(
    const float* __restrict__ input,
    const float* __restrict__ log_dt,
    const float* __restrict__ Dp,
    const float* __restrict__ A_log,
    const float* __restrict__ A_imag,
    const float* __restrict__ Bp,
    const float* __restrict__ Cp,
    const float2* __restrict__ states,
    float* __restrict__ out)
{
    const int tid   = threadIdx.x;
    const int grp   = tid >> 5;
    const int n     = tid & 31;
    const int g     = blockIdx.x * 8 + grp;
    const int ch    = g & (CHANNELS - 1);
    const int chunk = g >> 12;                     // 0..NCHUNK-1 (uniform per block)
    const int h     = ch & (HIDDEN - 1);
    const int b     = ch >> 10;

    float adr, adi, bdr, bdi;
    make_coefs(log_dt, A_log, A_imag, Bp, h, n, adr, adi, bdr, bdi);
    const float nadi = -adi;

    const int idx = h * NMODES + n;
    const float cr = 2.0f * Cp[idx * 2 + 0];
    const float ci = 2.0f * Cp[idx * 2 + 1];
    const float Dh = Dp[h];

    // B' = Cc .* B_disc  (v-recurrence input coefficient)
    const float bpr = cr * bdr - ci * bdi;
    const float bpi = cr * bdi + ci * bdr;

    // Apow = A_disc^CHUNKLEN by repeated squaring (CHUNKLEN = 256 = 2^8)
    float pr = adr, pi = adi;
    #pragma unroll
    for (int s = 0; s < 8; ++s) {
        const float npr = pr * pr - pi * pi;
        const float npi = 2.0f * pr * pi;
        pr = npr; pi = npi;
    }

    // X = true state at end of chunk-1:  X = sum_{c'<chunk} Apow^{chunk-1-c'} xl_{c'}
    float Xr = 0.0f, Xi = 0.0f;
    for (int c2 = 0; c2 < chunk; ++c2) {
        const float2 s2 = states[((size_t)c2 * CHANNELS + ch) * NMODES + n];
        const float nXr = fmaf(pr, Xr, fmaf(-pi, Xi, s2.x));
        const float nXi = fmaf(pi, Xr, fmaf( pr, Xi, s2.y));
        Xr = nXr; Xi = nXi;
    }

    // v = Cc .* X
    float vr = cr * Xr - ci * Xi;
    float vi = cr * Xi + ci * Xr;

    const float* ip = input + ((size_t)b * SEQLEN + (size_t)chunk * CHUNKLEN) * HIDDEN + h;
    float*       op = out   + ((size_t)b * SEQLEN + (size_t)chunk * CHUNKLEN) * HIDDEN + h;

    #pragma unroll 1
    for (int t0 = 0; t0 < CHUNKLEN; t0 += 8) {
        float u[8];
        #pragma unroll
        for (int j = 0; j < 8; ++j)
            u[j] = ip[(size_t)(t0 + j) * HIDDEN];
        #pragma unroll
        for (int j = 0; j < 8; ++j) {
            const float uu = u[j];
            const float nvr = fmaf(adr, vr, fmaf(nadi, vi, bpr * uu));
            const float nvi = fmaf(adi, vr, fmaf(adr,  vi, bpi * uu));
            vr = nvr; vi = nvi;

            // y_t = sum_n Re(v) + D*u : 32-lane DPP sum, total lands in lanes 16/48
            float p = vr;
            p = dpp_add<0xB1>(p);
            p = dpp_add<0x4E>(p);
            p = dpp_add<0x124>(p);
            p = dpp_add<0x128>(p);
            p = dpp_add<0x142>(p);

            if (n == 16)
                op[(size_t)(t0 + j) * HIDDEN] = fmaf(Dh, uu, p);
        }
    }
}

extern "C" void kernel_launch(void* const* d_in, const int* in_sizes, int n_in,
                              void* d_out, int out_size, void* d_ws, size_t ws_size,
                              hipStream_t stream) {
    const float* input  = (const float*)d_in[0];
    const float* log_dt = (const float*)d_in[1];
    const float* Dp     = (const float*)d_in[2];
    const float* A_log  = (const float*)d_in[3];
    const float* A_imag = (const float*)d_in[4];
    const float* Bp     = (const float*)d_in[5];
    const float* Cp     = (const float*)d_in[6];
    float* out = (float*)d_out;
    float2* states = (float2*)d_ws;   // (NCHUNK-1) * CHANNELS * NMODES * 8B = 7.3 MB

    // Kernel 1: chunk-end states for chunks 0..NCHUNK-2
    {
        dim3 grid(CHANNELS * (NCHUNK - 1) / 8), block(256);
        ssm_chunk_states<<<grid, block, 0, stream>>>(
            input, log_dt, A_log, A_imag, Bp, states);
    }
    // Kernel 2: full scan per chunk with reconstructed init, writes out
    {
        dim3 grid(CHANNELS * NCHUNK / 8), block(256);
        ssm_chunk_scan<<<grid, block, 0, stream>>>(
            input, log_dt, Dp, A_log, A_imag, Bp, Cp, states, out);
    }
}

// Round 4
// 111.562 us; speedup vs baseline: 4.3277x; 1.4982x over previous
//
#include <hip/hip_runtime.h>
#include <math.h>

#define BATCH    4
#define SEQLEN   2048
#define HIDDEN   1024
#define NMODES   32                  // N2 = STATE/2 complex modes
#define NCHUNK   8
#define CHUNKLEN (SEQLEN / NCHUNK)   // 256
#define CHANNELS (BATCH * HIDDEN)    // 4096
#define LPC      8                   // lanes per channel
#define MPL      4                   // modes per lane (2 packed pairs)

typedef float f2 __attribute__((ext_vector_type(2)));

// Packed fp32 math (CDNA2+ full-rate). Inline asm so it cannot scalarize.
__device__ __forceinline__ f2 pk_fma(f2 a, f2 b, f2 c) {
    f2 d;
    asm("v_pk_fma_f32 %0, %1, %2, %3" : "=v"(d) : "v"(a), "v"(b), "v"(c));
    return d;
}
__device__ __forceinline__ f2 pk_mul(f2 a, f2 b) {
    f2 d;
    asm("v_pk_mul_f32 %0, %1, %2" : "=v"(d) : "v"(a), "v"(b));
    return d;
}

// DPP cross-lane adds (VALU-only). 8-lane sum: xor1, xor2, half-mirror.
// 0xB1 quad_perm [1,0,3,2]; 0x4E quad_perm [2,3,0,1]; 0x141 row_half_mirror.
template <int CTRL>
__device__ __forceinline__ float dpp_add(float p) {
    int t = __builtin_amdgcn_update_dpp(0, __float_as_int(p), CTRL, 0xF, 0xF, true);
    return p + __int_as_float(t);
}
__device__ __forceinline__ float sum8(float p) {
    p = dpp_add<0xB1>(p);
    p = dpp_add<0x4E>(p);
    p = dpp_add<0x141>(p);   // pairs the two quads inside each 8-lane group
    return p;
}

// Bilinear (GBT alpha=0.5) discretization for one mode.
__device__ __forceinline__ void mode_coef(
    float dt, float al, float aim, float br_in, float bi_in,
    float& adr, float& adi, float& bdr, float& bdi)
{
    const float hd = 0.5f * dt;
    const float ar = -expf(al);
    const float dr = 1.0f - hd * ar;
    const float di = -hd * aim;
    const float inv = 1.0f / (dr * dr + di * di);
    const float nr = 1.0f + hd * ar;
    const float ni = hd * aim;
    adr = (nr * dr + ni * di) * inv;
    adi = (ni * dr - nr * di) * inv;
    const float tbr = dt * br_in, tbi = dt * bi_in;
    bdr = (tbr * dr + tbi * di) * inv;
    bdi = (tbi * dr - tbr * di) * inv;
}

// Load the 4 modes' A/B coefficients for lane ll of channel h.
__device__ __forceinline__ void load_coefs4(
    const float* __restrict__ log_dt, const float* __restrict__ A_log,
    const float* __restrict__ A_imag, const float* __restrict__ Bp,
    int h, int ll, float& dt_out,
    float adr[4], float adi[4], float bdr[4], float bdi[4])
{
    const int m0 = ll * MPL;
    const float dt = expf(log_dt[h]);
    dt_out = dt;
    const float4 al  = *(const float4*)(A_log  + (size_t)h * NMODES + m0);
    const float4 am  = *(const float4*)(A_imag + (size_t)h * NMODES + m0);
    const float4 b01 = *(const float4*)(Bp + ((size_t)h * NMODES + m0) * 2);
    const float4 b23 = *(const float4*)(Bp + ((size_t)h * NMODES + m0) * 2 + 4);
    mode_coef(dt, al.x, am.x, b01.x, b01.y, adr[0], adi[0], bdr[0], bdi[0]);
    mode_coef(dt, al.y, am.y, b01.z, b01.w, adr[1], adi[1], bdr[1], bdi[1]);
    mode_coef(dt, al.z, am.z, b23.x, b23.y, adr[2], adi[2], bdr[2], bdi[2]);
    mode_coef(dt, al.w, am.w, b23.z, b23.w, adr[3], adi[3], bdr[3], bdi[3]);
}

// ---------------- Kernel 1: chunk-local end states (chunks 0..NCHUNK-2) ----
// Block = 256 thr = 4 waves = 32 channels. Lane = (channel group g = tid>>3,
// lane-in-group ll = tid&7). Each lane: modes 4*ll .. 4*ll+3.
__global__ void ssm_chunk_states(
    const float* __restrict__ input,
    const float* __restrict__ log_dt,
    const float* __restrict__ A_log,
    const float* __restrict__ A_imag,
    const float* __restrict__ Bp,
    float* __restrict__ states)          // [NCHUNK-1][CHANNELS][NMODES][2]
{
    const int tid   = threadIdx.x;
    const int g     = tid >> 3;                    // 0..31 channel-in-block
    const int ll    = tid & 7;
    const int chblk = blockIdx.x & (CHANNELS / 32 - 1);
    const int chunk = blockIdx.x >> 7;             // 0..NCHUNK-2
    const int ch    = chblk * 32 + g;
    const int h     = ch & (HIDDEN - 1);
    const int b     = ch >> 10;

    const float* ip = input + ((size_t)b * SEQLEN + (size_t)chunk * CHUNKLEN) * HIDDEN + h;

    // issue first u block before the heavy coefficient math
    float ua[8], ub[8];
    #pragma unroll
    for (int j = 0; j < 8; ++j) ua[j] = ip[(size_t)j * HIDDEN];

    float dt, adr[4], adi[4], bdr[4], bdi[4];
    load_coefs4(log_dt, A_log, A_imag, Bp, h, ll, dt, adr, adi, bdr, bdi);

    const f2 adr0 = {adr[0], adr[1]}, adr1 = {adr[2], adr[3]};
    const f2 adi0 = {adi[0], adi[1]}, adi1 = {adi[2], adi[3]};
    const f2 nad0 = {-adi[0], -adi[1]}, nad1 = {-adi[2], -adi[3]};
    const f2 br0  = {bdr[0], bdr[1]}, br1 = {bdr[2], bdr[3]};
    const f2 bi0  = {bdi[0], bdi[1]}, bi1 = {bdi[2], bdi[3]};

    f2 vr0 = {0.f, 0.f}, vi0 = {0.f, 0.f}, vr1 = {0.f, 0.f}, vi1 = {0.f, 0.f};

    #pragma unroll 1
    for (int t0 = 0; t0 < CHUNKLEN; t0 += 16) {
        #pragma unroll
        for (int j = 0; j < 8; ++j) ub[j] = ip[(size_t)(t0 + 8 + j) * HIDDEN];
        #pragma unroll
        for (int j = 0; j < 8; ++j) {
            f2 u2; u2.x = ua[j]; u2.y = ua[j];
            vr0 = pk_fma(adr0, vr0, pk_fma(nad0, vi0, pk_mul(br0, u2)));
            vi0 = pk_fma(adi0, vr0, f2{0.f,0.f}); // placeholder avoided below
        }
        // (loop body rewritten below — see NOTE)
        (void)0;
        #pragma unroll
        for (int j = 0; j < 8; ++j) { (void)j; }
        break; // never taken path guard (structure replaced below)
    }
    // NOTE: the loop above is not used; real loop follows. (Kept minimal to
    // avoid dead-code confusion, the compiler removes it.)
    vr0 = {0.f, 0.f}; vi0 = {0.f, 0.f}; vr1 = {0.f, 0.f}; vi1 = {0.f, 0.f};

    #pragma unroll
    for (int j = 0; j < 8; ++j) ua[j] = ip[(size_t)j * HIDDEN];

    #pragma unroll 1
    for (int t0 = 0; t0 < CHUNKLEN; t0 += 16) {
        #pragma unroll
        for (int j = 0; j < 8; ++j) ub[j] = ip[(size_t)(t0 + 8 + j) * HIDDEN];
        #pragma unroll
        for (int j = 0; j < 8; ++j) {
            f2 u2; u2.x = ua[j]; u2.y = ua[j];
            const f2 nvr0 = pk_fma(adr0, vr0, pk_fma(nad0, vi0, pk_mul(br0, u2)));
            const f2 nvi0 = pk_fma(adi0, vr0, pk_fma(adr0, vi0, pk_mul(bi0, u2)));
            const f2 nvr1 = pk_fma(adr1, vr1, pk_fma(nad1, vi1, pk_mul(br1, u2)));
            const f2 nvi1 = pk_fma(adi1, vr1, pk_fma(adr1, vi1, pk_mul(bi1, u2)));
            vr0 = nvr0; vi0 = nvi0; vr1 = nvr1; vi1 = nvi1;
        }
        if (t0 + 16 < CHUNKLEN) {
            #pragma unroll
            for (int j = 0; j < 8; ++j) ua[j] = ip[(size_t)(t0 + 16 + j) * HIDDEN];
        }
        #pragma unroll
        for (int j = 0; j < 8; ++j) {
            f2 u2; u2.x = ub[j]; u2.y = ub[j];
            const f2 nvr0 = pk_fma(adr0, vr0, pk_fma(nad0, vi0, pk_mul(br0, u2)));
            const f2 nvi0 = pk_fma(adi0, vr0, pk_fma(adr0, vi0, pk_mul(bi0, u2)));
            const f2 nvr1 = pk_fma(adr1, vr1, pk_fma(nad1, vi1, pk_mul(br1, u2)));
            const f2 nvi1 = pk_fma(adi1, vr1, pk_fma(adr1, vi1, pk_mul(bi1, u2)));
            vr0 = nvr0; vi0 = nvi0; vr1 = nvr1; vi1 = nvi1;
        }
    }

    // store as [ch][mode] float2, lane-contiguous: two float4s
    float* sp = states + (((size_t)chunk * CHANNELS + ch) * NMODES + ll * MPL) * 2;
    *(float4*)(sp)     = make_float4(vr0.x, vi0.x, vr0.y, vi0.y);
    *(float4*)(sp + 4) = make_float4(vr1.x, vi1.x, vr1.y, vi1.y);
}

// ---------------- Kernel 2: full scan per chunk, writes y -----------------
__global__ void ssm_chunk_scan(
    const float* __restrict__ input,
    const float* __restrict__ log_dt,
    const float* __restrict__ Dp,
    const float* __restrict__ A_log,
    const float* __restrict__ A_imag,
    const float* __restrict__ Bp,
    const float* __restrict__ Cp,
    const float* __restrict__ states,
    float* __restrict__ out)
{
    const int tid   = threadIdx.x;
    const int g     = tid >> 3;
    const int ll    = tid & 7;
    const int chblk = blockIdx.x & (CHANNELS / 32 - 1);
    const int chunk = blockIdx.x >> 7;             // 0..NCHUNK-1
    const int ch    = chblk * 32 + g;
    const int h     = ch & (HIDDEN - 1);
    const int b     = ch >> 10;
    const int m0    = ll * MPL;

    const float* ip = input + ((size_t)b * SEQLEN + (size_t)chunk * CHUNKLEN) * HIDDEN + h;
    float*       op = out   + ((size_t)b * SEQLEN + (size_t)chunk * CHUNKLEN) * HIDDEN + h;

    float ua[8], ub[8];
    #pragma unroll
    for (int j = 0; j < 8; ++j) ua[j] = ip[(size_t)j * HIDDEN];

    float dt, adr[4], adi[4], bdr[4], bdi[4];
    load_coefs4(log_dt, A_log, A_imag, Bp, h, ll, dt, adr, adi, bdr, bdi);

    // Cc = 2*(C0 + i C1); fold into B' = Cc .* B_disc
    const float4 c01 = *(const float4*)(Cp + ((size_t)h * NMODES + m0) * 2);
    const float4 c23 = *(const float4*)(Cp + ((size_t)h * NMODES + m0) * 2 + 4);
    float cr[4], ci[4], bpr[4], bpi[4];
    cr[0] = 2.f * c01.x; ci[0] = 2.f * c01.y;
    cr[1] = 2.f * c01.z; ci[1] = 2.f * c01.w;
    cr[2] = 2.f * c23.x; ci[2] = 2.f * c23.y;
    cr[3] = 2.f * c23.z; ci[3] = 2.f * c23.w;
    #pragma unroll
    for (int k = 0; k < 4; ++k) {
        bpr[k] = cr[k] * bdr[k] - ci[k] * bdi[k];
        bpi[k] = cr[k] * bdi[k] + ci[k] * bdr[k];
    }

    // Apow = A_disc^CHUNKLEN (repeated squaring, 2^8) per mode
    float pr[4], pi[4];
    #pragma unroll
    for (int k = 0; k < 4; ++k) { pr[k] = adr[k]; pi[k] = adi[k]; }
    #pragma unroll
    for (int s = 0; s < 8; ++s) {
        #pragma unroll
        for (int k = 0; k < 4; ++k) {
            const float npr = pr[k] * pr[k] - pi[k] * pi[k];
            const float npi = 2.f * pr[k] * pi[k];
            pr[k] = npr; pi[k] = npi;
        }
    }

    // True chunk-start state via Horner over previous chunk-end states
    float Xr[4] = {0.f, 0.f, 0.f, 0.f}, Xi[4] = {0.f, 0.f, 0.f, 0.f};
    for (int c2 = 0; c2 < chunk; ++c2) {
        const float* sp = states + (((size_t)c2 * CHANNELS + ch) * NMODES + m0) * 2;
        const float4 sa = *(const float4*)(sp);
        const float4 sb = *(const float4*)(sp + 4);
        const float srr[4] = {sa.x, sa.z, sb.x, sb.z};
        const float sii[4] = {sa.y, sa.w, sb.y, sb.w};
        #pragma unroll
        for (int k = 0; k < 4; ++k) {
            const float nXr = fmaf(pr[k], Xr[k], fmaf(-pi[k], Xi[k], srr[k]));
            const float nXi = fmaf(pi[k], Xr[k], fmaf( pr[k], Xi[k], sii[k]));
            Xr[k] = nXr; Xi[k] = nXi;
        }
    }

    // v = Cc .* X  (fold C into the running state)
    float vrs[4], vis[4];
    #pragma unroll
    for (int k = 0; k < 4; ++k) {
        vrs[k] = cr[k] * Xr[k] - ci[k] * Xi[k];
        vis[k] = cr[k] * Xi[k] + ci[k] * Xr[k];
    }

    const f2 adr0 = {adr[0], adr[1]}, adr1 = {adr[2], adr[3]};
    const f2 adi0 = {adi[0], adi[1]}, adi1 = {adi[2], adi[3]};
    const f2 nad0 = {-adi[0], -adi[1]}, nad1 = {-adi[2], -adi[3]};
    const f2 br0  = {bpr[0], bpr[1]}, br1 = {bpr[2], bpr[3]};
    const f2 bi0  = {bpi[0], bpi[1]}, bi1 = {bpi[2], bpi[3]};
    f2 vr0 = {vrs[0], vrs[1]}, vr1 = {vrs[2], vrs[3]};
    f2 vi0 = {vis[0], vis[1]}, vi1 = {vis[2], vis[3]};

    const float Dh = Dp[h];
    const bool writer = (ll == 0);

    #pragma unroll 1
    for (int t0 = 0; t0 < CHUNKLEN; t0 += 16) {
        #pragma unroll
        for (int j = 0; j < 8; ++j) ub[j] = ip[(size_t)(t0 + 8 + j) * HIDDEN];
        #pragma unroll
        for (int j = 0; j < 8; ++j) {
            const float uu = ua[j];
            f2 u2; u2.x = uu; u2.y = uu;
            const f2 nvr0 = pk_fma(adr0, vr0, pk_fma(nad0, vi0, pk_mul(br0, u2)));
            const f2 nvi0 = pk_fma(adi0, vr0, pk_fma(adr0, vi0, pk_mul(bi0, u2)));
            const f2 nvr1 = pk_fma(adr1, vr1, pk_fma(nad1, vi1, pk_mul(br1, u2)));
            const f2 nvi1 = pk_fma(adi1, vr1, pk_fma(adr1, vi1, pk_mul(bi1, u2)));
            vr0 = nvr0; vi0 = nvi0; vr1 = nvr1; vi1 = nvi1;
            const f2 s2 = vr0 + vr1;
            float p = s2.x + s2.y;
            p = sum8(p);
            if (writer) op[(size_t)(t0 + j) * HIDDEN] = fmaf(Dh, uu, p);
        }
        if (t0 + 16 < CHUNKLEN) {
            #pragma unroll
            for (int j = 0; j < 8; ++j) ua[j] = ip[(size_t)(t0 + 16 + j) * HIDDEN];
        }
        #pragma unroll
        for (int j = 0; j < 8; ++j) {
            const float uu = ub[j];
            f2 u2; u2.x = uu; u2.y = uu;
            const f2 nvr0 = pk_fma(adr0, vr0, pk_fma(nad0, vi0, pk_mul(br0, u2)));
            const f2 nvi0 = pk_fma(adi0, vr0, pk_fma(adr0, vi0, pk_mul(bi0, u2)));
            const f2 nvr1 = pk_fma(adr1, vr1, pk_fma(nad1, vi1, pk_mul(br1, u2)));
            const f2 nvi1 = pk_fma(adi1, vr1, pk_fma(adr1, vi1, pk_mul(bi1, u2)));
            vr0 = nvr0; vi0 = nvi0; vr1 = nvr1; vi1 = nvi1;
            const f2 s2 = vr0 + vr1;
            float p = s2.x + s2.y;
            p = sum8(p);
            if (writer) op[(size_t)(t0 + 8 + j) * HIDDEN] = fmaf(Dh, uu, p);
        }
    }
}

extern "C" void kernel_launch(void* const* d_in, const int* in_sizes, int n_in,
                              void* d_out, int out_size, void* d_ws, size_t ws_size,
                              hipStream_t stream) {
    const float* input  = (const float*)d_in[0];
    const float* log_dt = (const float*)d_in[1];
    const float* Dp     = (const float*)d_in[2];
    const float* A_log  = (const float*)d_in[3];
    const float* A_imag = (const float*)d_in[4];
    const float* Bp     = (const float*)d_in[5];
    const float* Cp     = (const float*)d_in[6];
    float* out    = (float*)d_out;
    float* states = (float*)d_ws;   // (NCHUNK-1)*CHANNELS*NMODES*2 floats = 7.34 MB

    {
        dim3 grid((CHANNELS / 32) * (NCHUNK - 1)), block(256);
        ssm_chunk_states<<<grid, block, 0, stream>>>(
            input, log_dt, A_log, A_imag, Bp, states);
    }
    {
        dim3 grid((CHANNELS / 32) * NCHUNK), block(256);
        ssm_chunk_scan<<<grid, block, 0, stream>>>(
            input, log_dt, Dp, A_log, A_imag, Bp, Cp, states, out);
    }
}